// Round 5
// baseline (263.541 us; speedup 1.0000x reference)
//
#include <hip/hip_runtime.h>
#include <hip/hip_bf16.h>

typedef __attribute__((ext_vector_type(4))) float floatx4;
typedef __attribute__((ext_vector_type(8))) short short8;

#define HIDDEN 256
#define NOUT 16384   // GDIM*GDIM*GROUPS = 64*64*4

static __device__ __forceinline__ short bf16bits(float x) {
    __hip_bfloat16 h = __float2bfloat16(x);
    return __builtin_bit_cast(short, h);
}

// channel permutation: original channel c -> permuted position p (kB's fragment read order)
static __device__ __forceinline__ int permc(int c) {
    const int g = c >> 12, e = (c >> 6) & 63, d = c & 63;
    const int nt = e >> 4, lq = e & 15, ks = (d >> 5) & 1, quad = (d >> 3) & 3, j = d & 7;
    return ((((g << 2) | nt) << 1 | ks) << 9) | (((quad << 4) | lq) << 3) | j;
}
// inverse: permuted position p -> original channel c
static __device__ __forceinline__ int invperm(int p) {
    const int blk = p >> 9, g = blk >> 3, nt = (blk >> 1) & 3, ks = blk & 1;
    const int r = (p >> 3) & 63, quad = r >> 4, lq = r & 15, j = p & 7;
    return g * 4096 + (nt * 16 + lq) * 64 + ks * 32 + quad * 8 + j;
}

// ---------------- kPrep: Wg fp32 -> WgTp (bf16, transposed, channel-permuted); qc -> bf16 ----------------
__global__ __launch_bounds__(256) void kPrep(
    const float* __restrict__ Wg, short* __restrict__ WgTp,
    const float* __restrict__ qc, short* __restrict__ qcb, int n4)
{
    __shared__ short t[64 * 68];
    const int tid = threadIdx.x;

    if (blockIdx.x < 1024) {
        const int n0 = (blockIdx.x & 255) * 64, k0 = (blockIdx.x >> 8) * 64;
        // phase 1: coalesced read along n, write t[kl][nl] (bf16)
        const int r  = tid >> 4;
        const int c4 = tid & 15;
        #pragma unroll
        for (int i = 0; i < 4; ++i) {
            const int kl = r + i * 16;
            float4 f = *reinterpret_cast<const float4*>(Wg + (size_t)(k0 + kl) * NOUT + n0 + c4 * 4);
            short4 v;
            v.x = bf16bits(f.x); v.y = bf16bits(f.y); v.z = bf16bits(f.z); v.w = bf16bits(f.w);
            *reinterpret_cast<short4*>(&t[kl * 68 + c4 * 4]) = v;
        }
        __syncthreads();
        // phase 2: gather k-contiguous, b128 store to PERMUTED row
        #pragma unroll
        for (int h = 0; h < 2; ++h) {
            const int id = tid + h * 256;
            const int nl = id >> 3, kc = id & 7;
            short8 v;
            #pragma unroll
            for (int j = 0; j < 8; ++j) v[j] = t[(kc * 8 + j) * 68 + nl];
            const int prow = permc(n0 + nl);
            *reinterpret_cast<short8*>(WgTp + (size_t)prow * HIDDEN + k0 + kc * 8) = v;
        }
    } else {
        const int i = (blockIdx.x - 1024) * 256 + tid;
        if (i < n4) {
            float4 f = reinterpret_cast<const float4*>(qc)[i];
            short4 v;
            v.x = bf16bits(f.x); v.y = bf16bits(f.y); v.z = bf16bits(f.z); v.w = bf16bits(f.w);
            reinterpret_cast<short4*>(qcb)[i] = v;
        }
    }
}

// ---------------- kA4: wdyn_perm[M,16384] = bf16(qcb @ WgTp^T + bg∘inv) ----------------
// 128x128 tile, 256 threads = 4 waves (2x2). NO LDS in main loop: fragments direct from
// L2-resident qcb/WgTp. K=256 fully unrolled (8 MFMA steps), zero barriers until epilogue.
__global__ __launch_bounds__(256) void kA4(
    const short* __restrict__ qcb, const short* __restrict__ WgTp,
    const float* __restrict__ bg, short* __restrict__ wdyn, int M)
{
    __shared__ short Cs[64 * 128];   // 16 KB epilogue restage

    const int tid  = threadIdx.x;
    const int wave = tid >> 6, lane = tid & 63;
    const int lq   = lane & 15, quad = lane >> 4;
    const int wm   = wave >> 1, wn = wave & 1;
    const int m0   = blockIdx.x * 128;
    const int n0   = blockIdx.y * 128;

    const short* aP[4];
    const short* bP[4];
    #pragma unroll
    for (int i = 0; i < 4; ++i) {
        int ra = m0 + wm * 64 + i * 16 + lq; if (ra >= M) ra = M - 1;
        aP[i] = qcb  + (size_t)ra * HIDDEN + quad * 8;
        bP[i] = WgTp + (size_t)(n0 + wn * 64 + i * 16 + lq) * HIDDEN + quad * 8;
    }

    floatx4 acc[4][4];
    #pragma unroll
    for (int i = 0; i < 4; ++i)
        #pragma unroll
        for (int j = 0; j < 4; ++j) acc[i][j] = (floatx4){0.f, 0.f, 0.f, 0.f};

    #pragma unroll
    for (int s = 0; s < 8; ++s) {
        short8 a[4], b[4];
        #pragma unroll
        for (int i = 0; i < 4; ++i) a[i] = *reinterpret_cast<const short8*>(aP[i] + s * 32);
        #pragma unroll
        for (int j = 0; j < 4; ++j) b[j] = *reinterpret_cast<const short8*>(bP[j] + s * 32);
        #pragma unroll
        for (int i = 0; i < 4; ++i)
            #pragma unroll
            for (int j = 0; j < 4; ++j)
                acc[i][j] = __builtin_amdgcn_mfma_f32_16x16x32_bf16(a[i], b[j], acc[i][j], 0, 0, 0);
    }

    // bias via inverse channel permutation (bg is 64 KB, cache-resident)
    float bv[4];
    #pragma unroll
    for (int j = 0; j < 4; ++j) bv[j] = bg[invperm(n0 + wn * 64 + j * 16 + lq)];

    // epilogue: restage through LDS, coalesced bf16 stores
    #pragma unroll
    for (int half = 0; half < 2; ++half) {
        __syncthreads();
        if (wm == half) {
            #pragma unroll
            for (int j = 0; j < 4; ++j)
                #pragma unroll
                for (int i = 0; i < 4; ++i)
                    #pragma unroll
                    for (int r = 0; r < 4; ++r)
                        Cs[(i * 16 + quad * 4 + r) * 128 + wn * 64 + j * 16 + lq] =
                            bf16bits(acc[i][j][r] + bv[j]);
        }
        __syncthreads();
        #pragma unroll
        for (int t = 0; t < 4; ++t) {
            const int id = t * 256 + tid;
            const int mr = id >> 4, ch = id & 15;
            const int grow = m0 + half * 64 + mr;
            if (grow < M)
                *reinterpret_cast<short8*>(&wdyn[(size_t)grow * NOUT + n0 + ch * 8]) =
                    *reinterpret_cast<const short8*>(&Cs[mr * 128 + ch * 8]);
        }
    }
}

// ---------------- kB4: per (b,n): grouped mix + in-register LayerNorm + ReLU ----------------
// wdyn is channel-permuted so every b-fragment load is one contiguous 1 KB wave transaction.
__global__ __launch_bounds__(256) void kB4(
    const float* __restrict__ x, const short* __restrict__ wdyn,
    const float* __restrict__ gamma, const float* __restrict__ beta,
    float* __restrict__ out)
{
    __shared__ float red[2][4][4][2][2];   // [mtile][quad][r][gp][s/ss] = 512 B

    const int tid  = threadIdx.x;
    const int bnq  = blockIdx.x;
    const int wave = tid >> 6, lane = tid & 63;
    const int lq   = lane & 15, quad = lane >> 4;
    const int mtile = wave & 1, gp = wave >> 1;

    const float* xr = x + (size_t)bnq * (32 * HIDDEN) + (mtile * 16 + lq) * HIDDEN;
    const short* wr = wdyn + (size_t)bnq * NOUT;

    // a-frags: x row, fp32 -> bf16 (nontemporal: streamed once)
    short8 afr[2][2];
    #pragma unroll
    for (int gi = 0; gi < 2; ++gi) {
        const int g = gp * 2 + gi;
        #pragma unroll
        for (int ks = 0; ks < 2; ++ks) {
            const floatx4* s = reinterpret_cast<const floatx4*>(xr + g * 64 + ks * 32 + quad * 8);
            const floatx4 f0 = __builtin_nontemporal_load(s);
            const floatx4 f1 = __builtin_nontemporal_load(s + 1);
            short8 v;
            v[0]=bf16bits(f0[0]); v[1]=bf16bits(f0[1]); v[2]=bf16bits(f0[2]); v[3]=bf16bits(f0[3]);
            v[4]=bf16bits(f1[0]); v[5]=bf16bits(f1[1]); v[6]=bf16bits(f1[2]); v[7]=bf16bits(f1[3]);
            afr[gi][ks] = v;
        }
    }

    floatx4 acc[2][4];
    #pragma unroll
    for (int gi = 0; gi < 2; ++gi)
        #pragma unroll
        for (int nt = 0; nt < 4; ++nt) acc[gi][nt] = (floatx4){0.f, 0.f, 0.f, 0.f};

    #pragma unroll
    for (int gi = 0; gi < 2; ++gi) {
        const int g = gp * 2 + gi;
        #pragma unroll
        for (int ks = 0; ks < 2; ++ks) {
            #pragma unroll
            for (int nt = 0; nt < 4; ++nt) {
                // contiguous: block (g,nt,ks) at offset blk*512 elems, lane*8 within
                const short8 b = *reinterpret_cast<const short8*>(
                    wr + (((((g << 2) | nt) << 1) | ks) << 9) + lane * 8);
                acc[gi][nt] = __builtin_amdgcn_mfma_f32_16x16x32_bf16(afr[gi][ks], b, acc[gi][nt], 0, 0, 0);
            }
        }
    }

    // in-register LN reduction
    float s[4], ss[4];
    #pragma unroll
    for (int r = 0; r < 4; ++r) { s[r] = 0.f; ss[r] = 0.f; }
    #pragma unroll
    for (int gi = 0; gi < 2; ++gi)
        #pragma unroll
        for (int nt = 0; nt < 4; ++nt)
            #pragma unroll
            for (int r = 0; r < 4; ++r) {
                const float v = acc[gi][nt][r];
                s[r] += v; ss[r] += v * v;
            }
    #pragma unroll
    for (int off = 1; off < 16; off <<= 1) {
        #pragma unroll
        for (int r = 0; r < 4; ++r) {
            s[r]  += __shfl_xor(s[r],  off);
            ss[r] += __shfl_xor(ss[r], off);
        }
    }
    if (lq == 0) {
        #pragma unroll
        for (int r = 0; r < 4; ++r) {
            red[mtile][quad][r][gp][0] = s[r];
            red[mtile][quad][r][gp][1] = ss[r];
        }
    }
    __syncthreads();

    float mu[4], rs[4];
    #pragma unroll
    for (int r = 0; r < 4; ++r) {
        const float S  = s[r]  + red[mtile][quad][r][gp ^ 1][0];
        const float SS = ss[r] + red[mtile][quad][r][gp ^ 1][1];
        mu[r] = S * (1.f / 256.f);
        float var = SS * (1.f / 256.f) - mu[r] * mu[r];
        var = fmaxf(var, 0.f);
        rs[r] = rsqrtf(var + 1e-5f);
    }

    // normalize + affine + relu, nontemporal stores
    float* orow = out + (size_t)bnq * (32 * HIDDEN);
    #pragma unroll
    for (int gi = 0; gi < 2; ++gi) {
        const int g = gp * 2 + gi;
        #pragma unroll
        for (int nt = 0; nt < 4; ++nt) {
            const int c = g * 64 + nt * 16 + lq;
            const float gm = gamma[c], bt = beta[c];
            #pragma unroll
            for (int r = 0; r < 4; ++r) {
                const int p = mtile * 16 + quad * 4 + r;
                const float v = fmaxf((acc[gi][nt][r] - mu[r]) * rs[r] * gm + bt, 0.f);
                __builtin_nontemporal_store(v, &orow[p * HIDDEN + c]);
            }
        }
    }
}

extern "C" void kernel_launch(void* const* d_in, const int* in_sizes, int n_in,
                              void* d_out, int out_size, void* d_ws, size_t ws_size,
                              hipStream_t stream)
{
    const float* x     = (const float*)d_in[0];
    const float* qc    = (const float*)d_in[1];
    const float* Wg    = (const float*)d_in[2];
    const float* bg    = (const float*)d_in[3];
    const float* gamma = (const float*)d_in[4];
    const float* beta  = (const float*)d_in[5];
    float* out = (float*)d_out;

    const int M = in_sizes[1] / HIDDEN;   // B*N = 2400

    // workspace layout (bytes)
    char* ws = (char*)d_ws;
    short* wdyn = (short*)ws;                                    // M*16384*2
    short* WgTp = (short*)(ws + (size_t)M * NOUT * 2);           // 16384*256*2
    short* qcb  = (short*)(ws + (size_t)M * NOUT * 2 + (size_t)NOUT * HIDDEN * 2);

    const int n4 = (M * HIDDEN) / 4;
    const int prepBlocks = 1024 + (n4 + 255) / 256;
    kPrep<<<prepBlocks, 256, 0, stream>>>(Wg, WgTp, qc, qcb, n4);

    kA4<<<dim3((M + 127) / 128, NOUT / 128), 256, 0, stream>>>(qcb, WgTp, bg, wdyn, M);

    kB4<<<M, 256, 0, stream>>>(x, wdyn, gamma, beta, out);
}

// Round 6
// 221.555 us; speedup vs baseline: 1.1895x; 1.1895x over previous
//
#include <hip/hip_runtime.h>
#include <hip/hip_bf16.h>

typedef __attribute__((ext_vector_type(4))) float floatx4;
typedef __attribute__((ext_vector_type(8))) short short8;

#define HIDDEN 256
#define NOUT 16384   // GDIM*GDIM*GROUPS = 64*64*4

static __device__ __forceinline__ short bf16bits(float x) {
    __hip_bfloat16 h = __float2bfloat16(x);
    return __builtin_bit_cast(short, h);
}

#define GLDS16(gsrc, ldst) \
    __builtin_amdgcn_global_load_lds((const __attribute__((address_space(1))) void*)(gsrc), \
                                     (__attribute__((address_space(3))) void*)(ldst), 16, 0, 0)

// channel permutation: original channel c -> permuted position p (kB's fragment read order)
static __device__ __forceinline__ int permc(int c) {
    const int g = c >> 12, e = (c >> 6) & 63, d = c & 63;
    const int nt = e >> 4, lq = e & 15, ks = (d >> 5) & 1, quad = (d >> 3) & 3, j = d & 7;
    return ((((g << 2) | nt) << 1 | ks) << 9) | (((quad << 4) | lq) << 3) | j;
}
// inverse: permuted position p -> original channel c
static __device__ __forceinline__ int invperm(int p) {
    const int blk = p >> 9, g = blk >> 3, nt = (blk >> 1) & 3, ks = blk & 1;
    const int r = (p >> 3) & 63, quad = r >> 4, lq = r & 15, j = p & 7;
    return g * 4096 + (nt * 16 + lq) * 64 + ks * 32 + quad * 8 + j;
}

// ---------------- kPrep: Wg fp32 -> WgTp (bf16, transposed, channel-permuted); qc -> bf16 ----------------
__global__ __launch_bounds__(256) void kPrep(
    const float* __restrict__ Wg, short* __restrict__ WgTp,
    const float* __restrict__ qc, short* __restrict__ qcb, int n4)
{
    __shared__ short t[64 * 68];
    const int tid = threadIdx.x;

    if (blockIdx.x < 1024) {
        const int n0 = (blockIdx.x & 255) * 64, k0 = (blockIdx.x >> 8) * 64;
        // phase 1: coalesced read along n, write t[kl][nl] (bf16)
        const int r  = tid >> 4;
        const int c4 = tid & 15;
        #pragma unroll
        for (int i = 0; i < 4; ++i) {
            const int kl = r + i * 16;
            float4 f = *reinterpret_cast<const float4*>(Wg + (size_t)(k0 + kl) * NOUT + n0 + c4 * 4);
            short4 v;
            v.x = bf16bits(f.x); v.y = bf16bits(f.y); v.z = bf16bits(f.z); v.w = bf16bits(f.w);
            *reinterpret_cast<short4*>(&t[kl * 68 + c4 * 4]) = v;
        }
        __syncthreads();
        // phase 2: gather k-contiguous, b128 store to PERMUTED row
        #pragma unroll
        for (int h = 0; h < 2; ++h) {
            const int id = tid + h * 256;
            const int nl = id >> 3, kc = id & 7;
            short8 v;
            #pragma unroll
            for (int j = 0; j < 8; ++j) v[j] = t[(kc * 8 + j) * 68 + nl];
            const int prow = permc(n0 + nl);
            *reinterpret_cast<short8*>(WgTp + (size_t)prow * HIDDEN + k0 + kc * 8) = v;
        }
    } else {
        const int i = (blockIdx.x - 1024) * 256 + tid;
        if (i < n4) {
            float4 f = reinterpret_cast<const float4*>(qc)[i];
            short4 v;
            v.x = bf16bits(f.x); v.y = bf16bits(f.y); v.z = bf16bits(f.z); v.w = bf16bits(f.w);
            reinterpret_cast<short4*>(qcb)[i] = v;
        }
    }
}

// ---------------- kA5: wdyn_perm[M,16384] = bf16(qcb @ WgTp^T + bg∘inv) ----------------
// 128x128 tile, BK=64, 256 threads = 4 waves (2x2). Coalesced global_load_lds staging with
// source-side XOR swizzle; LDS-restaged epilogue for coalesced bf16 stores.
__global__ __launch_bounds__(256) void kA5(
    const short* __restrict__ qcb, const short* __restrict__ WgTp,
    const float* __restrict__ bg, short* __restrict__ wdyn, int M)
{
    __shared__ short As[128 * 64];   // 16 KB, [row][k-chunk^swz]
    __shared__ short Bs[128 * 64];   // 16 KB

    const int tid  = threadIdx.x;
    const int wave = tid >> 6, lane = tid & 63;
    const int lq   = lane & 15, quad = lane >> 4;
    const int wm   = wave >> 1, wn = wave & 1;
    const int m0   = blockIdx.x * 128;
    const int n0   = blockIdx.y * 128;

    // staging: 1024 16B-chunks per buffer per iter; 4 GLDS per thread per buffer.
    // LDS slot (row, c) holds global k-chunk (c ^ (row&7)) -> source carries the swizzle.
    const short* aSrc[4]; const short* bSrc[4];
    short* aDst[4]; short* bDst[4];
    #pragma unroll
    for (int t = 0; t < 4; ++t) {
        const int chunk = t * 256 + wave * 64 + lane;
        const int row = chunk >> 3, kc = chunk & 7;
        const int kcs = kc ^ (row & 7);
        int rA = m0 + row; if (rA >= M) rA = M - 1;
        aSrc[t] = qcb  + (size_t)rA * HIDDEN + kcs * 8;
        bSrc[t] = WgTp + (size_t)(n0 + row) * HIDDEN + kcs * 8;
        aDst[t] = &As[(t * 256 + wave * 64) * 8];   // wave-uniform; HW adds lane*16B
        bDst[t] = &Bs[(t * 256 + wave * 64) * 8];
    }

    // fragment LDS offsets (shorts), constant across iters
    int aOff[2][4], bOff[2][4];
    #pragma unroll
    for (int ks = 0; ks < 2; ++ks)
        #pragma unroll
        for (int i = 0; i < 4; ++i) {
            const int ra = wm * 64 + i * 16 + lq;
            aOff[ks][i] = ra * 64 + (((ks * 4 + quad) ^ (ra & 7)) * 8);
            const int rb = wn * 64 + i * 16 + lq;
            bOff[ks][i] = rb * 64 + (((ks * 4 + quad) ^ (rb & 7)) * 8);
        }

    floatx4 acc[4][4];
    #pragma unroll
    for (int i = 0; i < 4; ++i)
        #pragma unroll
        for (int j = 0; j < 4; ++j) acc[i][j] = (floatx4){0.f, 0.f, 0.f, 0.f};

    for (int it = 0; it < 4; ++it) {
        #pragma unroll
        for (int t = 0; t < 4; ++t) {
            GLDS16(aSrc[t], aDst[t]);
            GLDS16(bSrc[t], bDst[t]);
            aSrc[t] += 64; bSrc[t] += 64;
        }
        __syncthreads();

        #pragma unroll
        for (int ks = 0; ks < 2; ++ks) {
            short8 a[4], b[4];
            #pragma unroll
            for (int i = 0; i < 4; ++i) a[i] = *reinterpret_cast<const short8*>(&As[aOff[ks][i]]);
            #pragma unroll
            for (int j = 0; j < 4; ++j) b[j] = *reinterpret_cast<const short8*>(&Bs[bOff[ks][j]]);
            #pragma unroll
            for (int i = 0; i < 4; ++i)
                #pragma unroll
                for (int j = 0; j < 4; ++j)
                    acc[i][j] = __builtin_amdgcn_mfma_f32_16x16x32_bf16(a[i], b[j], acc[i][j], 0, 0, 0);
        }
        __syncthreads();
    }

    // bias via inverse channel permutation (bg is 64 KB, cache-resident)
    float bv[4];
    #pragma unroll
    for (int j = 0; j < 4; ++j) bv[j] = bg[invperm(n0 + wn * 64 + j * 16 + lq)];

    // epilogue: restage through LDS (reuse As as 64x128 bf16), coalesced stores
    short* Cs = As;
    #pragma unroll
    for (int half = 0; half < 2; ++half) {
        if (half) __syncthreads();
        if (wm == half) {
            #pragma unroll
            for (int j = 0; j < 4; ++j)
                #pragma unroll
                for (int i = 0; i < 4; ++i)
                    #pragma unroll
                    for (int r = 0; r < 4; ++r)
                        Cs[(i * 16 + quad * 4 + r) * 128 + wn * 64 + j * 16 + lq] =
                            bf16bits(acc[i][j][r] + bv[j]);
        }
        __syncthreads();
        #pragma unroll
        for (int t = 0; t < 4; ++t) {
            const int id = t * 256 + tid;
            const int mr = id >> 4, ch = id & 15;
            const int grow = m0 + half * 64 + mr;
            if (grow < M)
                *reinterpret_cast<short8*>(&wdyn[(size_t)grow * NOUT + n0 + ch * 8]) =
                    *reinterpret_cast<const short8*>(&Cs[mr * 128 + ch * 8]);
        }
    }
}

// ---------------- kB4: per (b,n): grouped mix + in-register LayerNorm + ReLU ----------------
// wdyn is channel-permuted so every b-fragment load is one contiguous 1 KB wave transaction.
__global__ __launch_bounds__(256) void kB4(
    const float* __restrict__ x, const short* __restrict__ wdyn,
    const float* __restrict__ gamma, const float* __restrict__ beta,
    float* __restrict__ out)
{
    __shared__ float red[2][4][4][2][2];   // [mtile][quad][r][gp][s/ss] = 512 B

    const int tid  = threadIdx.x;
    const int bnq  = blockIdx.x;
    const int wave = tid >> 6, lane = tid & 63;
    const int lq   = lane & 15, quad = lane >> 4;
    const int mtile = wave & 1, gp = wave >> 1;

    const float* xr = x + (size_t)bnq * (32 * HIDDEN) + (mtile * 16 + lq) * HIDDEN;
    const short* wr = wdyn + (size_t)bnq * NOUT;

    // a-frags: x row, fp32 -> bf16 (nontemporal: streamed once)
    short8 afr[2][2];
    #pragma unroll
    for (int gi = 0; gi < 2; ++gi) {
        const int g = gp * 2 + gi;
        #pragma unroll
        for (int ks = 0; ks < 2; ++ks) {
            const floatx4* s = reinterpret_cast<const floatx4*>(xr + g * 64 + ks * 32 + quad * 8);
            const floatx4 f0 = __builtin_nontemporal_load(s);
            const floatx4 f1 = __builtin_nontemporal_load(s + 1);
            short8 v;
            v[0]=bf16bits(f0[0]); v[1]=bf16bits(f0[1]); v[2]=bf16bits(f0[2]); v[3]=bf16bits(f0[3]);
            v[4]=bf16bits(f1[0]); v[5]=bf16bits(f1[1]); v[6]=bf16bits(f1[2]); v[7]=bf16bits(f1[3]);
            afr[gi][ks] = v;
        }
    }

    floatx4 acc[2][4];
    #pragma unroll
    for (int gi = 0; gi < 2; ++gi)
        #pragma unroll
        for (int nt = 0; nt < 4; ++nt) acc[gi][nt] = (floatx4){0.f, 0.f, 0.f, 0.f};

    #pragma unroll
    for (int gi = 0; gi < 2; ++gi) {
        const int g = gp * 2 + gi;
        #pragma unroll
        for (int ks = 0; ks < 2; ++ks) {
            #pragma unroll
            for (int nt = 0; nt < 4; ++nt) {
                // contiguous: block (g,nt,ks) at offset blk*512 elems, lane*8 within
                const short8 b = *reinterpret_cast<const short8*>(
                    wr + (((((g << 2) | nt) << 1) | ks) << 9) + lane * 8);
                acc[gi][nt] = __builtin_amdgcn_mfma_f32_16x16x32_bf16(afr[gi][ks], b, acc[gi][nt], 0, 0, 0);
            }
        }
    }

    // in-register LN reduction
    float s[4], ss[4];
    #pragma unroll
    for (int r = 0; r < 4; ++r) { s[r] = 0.f; ss[r] = 0.f; }
    #pragma unroll
    for (int gi = 0; gi < 2; ++gi)
        #pragma unroll
        for (int nt = 0; nt < 4; ++nt)
            #pragma unroll
            for (int r = 0; r < 4; ++r) {
                const float v = acc[gi][nt][r];
                s[r] += v; ss[r] += v * v;
            }
    #pragma unroll
    for (int off = 1; off < 16; off <<= 1) {
        #pragma unroll
        for (int r = 0; r < 4; ++r) {
            s[r]  += __shfl_xor(s[r],  off);
            ss[r] += __shfl_xor(ss[r], off);
        }
    }
    if (lq == 0) {
        #pragma unroll
        for (int r = 0; r < 4; ++r) {
            red[mtile][quad][r][gp][0] = s[r];
            red[mtile][quad][r][gp][1] = ss[r];
        }
    }
    __syncthreads();

    float mu[4], rs[4];
    #pragma unroll
    for (int r = 0; r < 4; ++r) {
        const float S  = s[r]  + red[mtile][quad][r][gp ^ 1][0];
        const float SS = ss[r] + red[mtile][quad][r][gp ^ 1][1];
        mu[r] = S * (1.f / 256.f);
        float var = SS * (1.f / 256.f) - mu[r] * mu[r];
        var = fmaxf(var, 0.f);
        rs[r] = rsqrtf(var + 1e-5f);
    }

    // normalize + affine + relu, nontemporal stores
    float* orow = out + (size_t)bnq * (32 * HIDDEN);
    #pragma unroll
    for (int gi = 0; gi < 2; ++gi) {
        const int g = gp * 2 + gi;
        #pragma unroll
        for (int nt = 0; nt < 4; ++nt) {
            const int c = g * 64 + nt * 16 + lq;
            const float gm = gamma[c], bt = beta[c];
            #pragma unroll
            for (int r = 0; r < 4; ++r) {
                const int p = mtile * 16 + quad * 4 + r;
                const float v = fmaxf((acc[gi][nt][r] - mu[r]) * rs[r] * gm + bt, 0.f);
                __builtin_nontemporal_store(v, &orow[p * HIDDEN + c]);
            }
        }
    }
}

extern "C" void kernel_launch(void* const* d_in, const int* in_sizes, int n_in,
                              void* d_out, int out_size, void* d_ws, size_t ws_size,
                              hipStream_t stream)
{
    const float* x     = (const float*)d_in[0];
    const float* qc    = (const float*)d_in[1];
    const float* Wg    = (const float*)d_in[2];
    const float* bg    = (const float*)d_in[3];
    const float* gamma = (const float*)d_in[4];
    const float* beta  = (const float*)d_in[5];
    float* out = (float*)d_out;

    const int M = in_sizes[1] / HIDDEN;   // B*N = 2400

    // workspace layout (bytes)
    char* ws = (char*)d_ws;
    short* wdyn = (short*)ws;                                    // M*16384*2
    short* WgTp = (short*)(ws + (size_t)M * NOUT * 2);           // 16384*256*2
    short* qcb  = (short*)(ws + (size_t)M * NOUT * 2 + (size_t)NOUT * HIDDEN * 2);

    const int n4 = (M * HIDDEN) / 4;
    const int prepBlocks = 1024 + (n4 + 255) / 256;
    kPrep<<<prepBlocks, 256, 0, stream>>>(Wg, WgTp, qc, qcb, n4);

    kA5<<<dim3((M + 127) / 128, NOUT / 128), 256, 0, stream>>>(qcb, WgTp, bg, wdyn, M);

    kB4<<<M, 256, 0, stream>>>(x, wdyn, gamma, beta, out);
}